// Round 9
// baseline (260.536 us; speedup 1.0000x reference)
//
#include <hip/hip_runtime.h>
#include <hip/hip_bf16.h>

#define B_SZ 8
#define N_Q 512
#define M_KV 4096
#define DIM 1024
#define INNER 512
#define NHEADS 8
#define HDIM 64

typedef __attribute__((ext_vector_type(4))) float floatx4;
typedef __attribute__((ext_vector_type(8))) short shortx8;
typedef __attribute__((ext_vector_type(4))) short shortx4;

__device__ inline unsigned short f2bf(float f) {
  union { float f; unsigned u; } x; x.f = f;
  unsigned r = x.u + 0x7FFFu + ((x.u >> 16) & 1u);
  return (unsigned short)(r >> 16);
}

__device__ inline shortx8 cvt8(floatx4 a, floatx4 b) {
  shortx8 h;
  h[0] = (short)f2bf(a[0]); h[1] = (short)f2bf(a[1]);
  h[2] = (short)f2bf(a[2]); h[3] = (short)f2bf(a[3]);
  h[4] = (short)f2bf(b[0]); h[5] = (short)f2bf(b[1]);
  h[6] = (short)f2bf(b[2]); h[7] = (short)f2bf(b[3]);
  return h;
}

__device__ inline void gload16(const void* g, void* l) {
  __builtin_amdgcn_global_load_lds(
      (const __attribute__((address_space(1))) void*)g,
      (__attribute__((address_space(3))) void*)l, 16, 0, 0);
}

// fp32 -> bf16 bulk convert (memory-bound, grid-stride)
__global__ void k_cvt_bf16(const float* __restrict__ src,
                           unsigned short* __restrict__ dst, long n) {
  long stride = (long)gridDim.x * 256 * 8;
  for (long i = ((long)blockIdx.x * 256 + threadIdx.x) * 8; i < n; i += stride) {
    floatx4 a = *reinterpret_cast<const floatx4*>(src + i);
    floatx4 b = *reinterpret_cast<const floatx4*>(src + i + 4);
    *reinterpret_cast<shortx8*>(dst + i) = cvt8(a, b);
  }
}

// All four weight transposes in ONE launch. z=0:Wq z=1:Wk z=2:Wv z=3:Wo.
__global__ void k_transpose_all(const float* __restrict__ Wq,
                                const float* __restrict__ Wk,
                                const float* __restrict__ Wv,
                                const float* __restrict__ Wo,
                                unsigned short* __restrict__ Wqt,
                                unsigned short* __restrict__ Wkvt,
                                unsigned short* __restrict__ Wot) {
  __shared__ unsigned short t[32][36];
  const int z = blockIdx.z;
  const float* W;
  unsigned short* Wt;
  int K, N;
  if (z == 0)      { W = Wq; Wt = Wqt;  K = 1024; N = 512; }
  else if (z == 1) { W = Wk; Wt = Wkvt; K = 1024; N = 512; }
  else if (z == 2) { W = Wv; Wt = Wkvt + (size_t)512 * 1024; K = 1024; N = 512; }
  else             { W = Wo; Wt = Wot;  K = 512;  N = 1024; }
  if ((int)blockIdx.x * 32 >= K || (int)blockIdx.y * 32 >= N) return;
  const int kt = blockIdx.x * 32, nt = blockIdx.y * 32;
  const int tr = threadIdx.x >> 3;
  const int tc = (threadIdx.x & 7) * 4;
  floatx4 v = *reinterpret_cast<const floatx4*>(&W[(long)(kt + tr) * N + nt + tc]);
  #pragma unroll
  for (int j = 0; j < 4; ++j) t[tr][tc + j] = f2bf(v[j]);
  __syncthreads();
  shortx4 o;
  #pragma unroll
  for (int j = 0; j < 4; ++j) o[j] = (short)t[tc + j][tr];
  *reinterpret_cast<shortx4*>(&Wt[(long)(nt + tr) * K + kt + tc]) = o;
}

// Fused K+V projection, counted-vmcnt pipeline: 256x256 tile, BK=32,
// 8 waves (2Mx4N, wave tile 128x64), FOUR LDS buffers (128KB), depth-3
// prefetch. Per K-tile: STAGE(t+3) -> vmcnt(12) (tile t's loads done,
// 12 newer stay in flight ACROSS barriers) -> s_barrier -> ds_read+MFMA
// -> lgkmcnt(0) -> s_barrier. Swizzle identical to R8 (verified, 0 confl).
__global__ __launch_bounds__(512, 2)
void k_gemm_kv(const unsigned short* __restrict__ Ah,
               const unsigned short* __restrict__ Wkvt,
               unsigned short* __restrict__ Kh,
               unsigned short* __restrict__ Vt) {
  __shared__ unsigned short As[4][8192];
  __shared__ unsigned short Bs[4][8192];
  const int tid = threadIdx.x;
  const int lane = tid & 63;
  const int w = tid >> 6;             // 0..7
  const int wr = w >> 2, wc = w & 3;  // 2 x 4
  const int fr = lane & 15, fc = lane >> 4;

  // XCD-chunked swizzle: 512 blocks -> 64/XCD; nt fastest (A-panel L2 share)
  const int L = ((blockIdx.x & 7) << 6) + (blockIdx.x >> 3);
  const int mt = L >> 2, nt = L & 3;
  const long arow0 = (long)mt << 8;
  const long bcol0 = (long)nt << 8;

  // gload lane geometry: row = base + (lane>>2), 16B slot = lane&3;
  // logical chunk to fetch = slot ^ ((row>>1)&3) = (l&3) ^ ((l>>3)&3)
  const int grow = lane >> 2;
  const int gchunk = (lane & 3) ^ ((lane >> 3) & 3);

  floatx4 acc[8][4] = {};

  #define STAGE(buf, kt_)                                                \
    { _Pragma("unroll")                                                  \
      for (int j = 0; j < 2; ++j) {                                      \
        const int rl = j * 128 + w * 16 + grow;                          \
        gload16(Ah + (arow0 + rl) * 1024 + (kt_) + gchunk * 8,           \
                &As[buf][(j * 128 + w * 16) * 32]);                      \
        gload16(Wkvt + (bcol0 + rl) * 1024 + (kt_) + gchunk * 8,         \
                &Bs[buf][(j * 128 + w * 16) * 32]);                      \
      } }

  // prologue: tiles 0,1,2 in flight (12 gloads/wave outstanding)
  STAGE(0, 0);
  STAGE(1, 32);
  STAGE(2, 64);

  for (int t = 0; t < 32; ++t) {
    const int cur = t & 3;
    if (t < 29) {
      STAGE((t + 3) & 3, (t + 3) << 5);
      asm volatile("s_waitcnt vmcnt(12)" ::: "memory");
    } else if (t == 29) {
      asm volatile("s_waitcnt vmcnt(8)" ::: "memory");
    } else if (t == 30) {
      asm volatile("s_waitcnt vmcnt(4)" ::: "memory");
    } else {
      asm volatile("s_waitcnt vmcnt(0)" ::: "memory");
    }
    __builtin_amdgcn_s_barrier();  // tile t fully visible block-wide

    shortx8 bf[4], af[8];
    #pragma unroll
    for (int n = 0; n < 4; ++n) {
      int row = wc * 64 + n * 16 + fr;
      bf[n] = *reinterpret_cast<const shortx8*>(
          &Bs[cur][row * 32 + ((fc ^ ((row >> 1) & 3)) * 8)]);
    }
    #pragma unroll
    for (int m = 0; m < 8; ++m) {
      int row = wr * 128 + m * 16 + fr;
      af[m] = *reinterpret_cast<const shortx8*>(
          &As[cur][row * 32 + ((fc ^ ((row >> 1) & 3)) * 8)]);
    }
    __builtin_amdgcn_s_setprio(1);
    #pragma unroll
    for (int m = 0; m < 8; ++m) {
      #pragma unroll
      for (int n = 0; n < 4; ++n)
        acc[m][n] = __builtin_amdgcn_mfma_f32_16x16x32_bf16(
            af[m], bf[n], acc[m][n], 0, 0, 0);
    }
    __builtin_amdgcn_s_setprio(0);
    asm volatile("s_waitcnt lgkmcnt(0)" ::: "memory");
    __builtin_amdgcn_s_barrier();  // reads of buf[cur] done; safe to overwrite
  }
  #undef STAGE

  // epilogue: split K / V^T store (branch uniform per block: nt<2 -> K)
  #pragma unroll
  for (int m = 0; m < 8; ++m) {
    #pragma unroll
    for (int n = 0; n < 4; ++n) {
      long gr0 = arow0 + wr * 128 + m * 16 + fc * 4;
      long gc = bcol0 + wc * 64 + n * 16 + fr;
      long b = gr0 >> 12, mm = gr0 & 4095;
      if (gc < 512) {
        long h = gc >> 6, d = gc & 63;
        #pragma unroll
        for (int r = 0; r < 4; ++r)
          Kh[((((b * 8 + h) << 12) + mm + r) << 6) + d] = f2bf(acc[m][n][r]);
      } else {
        long h = (gc - 512) >> 6, d = (gc - 512) & 63;
        shortx4 hv;
        #pragma unroll
        for (int r = 0; r < 4; ++r) hv[r] = (short)f2bf(acc[m][n][r]);
        *reinterpret_cast<shortx4*>(&Vt[(((b * 8 + h) * 64 + d) << 12) + mm]) = hv;
      }
    }
  }
}

// General GEMM (Q-projection, out-projection), unchanged from R8.
template<int MODE, bool ABF, int NCOL, int MBITS>
__global__ __launch_bounds__(512, 4)
void k_gemm(const void* __restrict__ Ap, const unsigned short* __restrict__ Bt,
            void* __restrict__ Cout, const float* __restrict__ bias,
            int M, int N, int K, float oscale) {
  __shared__ unsigned short As[2][128 * 32];
  __shared__ unsigned short Bs[2][256 * 32];
  const int tid = threadIdx.x;
  const int lane = tid & 63;
  const int w = tid >> 6;
  const int wr = w >> 2, wc = w & 3;

  const int cpx = gridDim.x >> 3;
  const int L = (blockIdx.x & 7) * cpx + (blockIdx.x >> 3);
  const long arow0 = (long)(L / NCOL) * 128;
  const long bcol0 = (long)(L % NCOL) * 256;

  const float* Af = (const float*)Ap;
  const unsigned short* Ah = (const unsigned short*)Ap;

  const int lsub = lane >> 2;
  const int lchunk = (lane & 3) ^ ((lane >> 3) & 3);
  const long brow0 = bcol0 + (w * 2 + 0) * 16 + lsub;
  const long brow1 = bcol0 + (w * 2 + 1) * 16 + lsub;
  const long ahrow = arow0 + w * 16 + lsub;
  const int arow = tid >> 2;
  const int acseg = tid & 3;
  const int aswz = arow * 32 + ((acseg ^ ((arow >> 1) & 3)) * 8);

  floatx4 acc[4][4] = {};

  #define STAGE_B(buf, kt)                                                   \
    {                                                                        \
      gload16(Bt + brow0 * K + (kt) + lchunk * 8, &Bs[buf][(w * 2) * 512]);  \
      gload16(Bt + brow1 * K + (kt) + lchunk * 8,                            \
              &Bs[buf][(w * 2 + 1) * 512]);                                  \
    }
  #define STAGE_AH(buf, kt) \
    gload16(Ah + ahrow * K + (kt) + lchunk * 8, &As[buf][w * 512]);

  if (ABF) {
    STAGE_AH(0, 0);
  } else {
    const float* src = Af + (arow0 + arow) * (long)K + acseg * 8;
    floatx4 a0 = *reinterpret_cast<const floatx4*>(src);
    floatx4 a1 = *reinterpret_cast<const floatx4*>(src + 4);
    *reinterpret_cast<shortx8*>(&As[0][aswz]) = cvt8(a0, a1);
  }
  STAGE_B(0, 0);
  __syncthreads();

  const int NK = K >> 5;
  for (int i = 0; i < NK; ++i) {
    const int cur = i & 1;
    const bool more = (i + 1) < NK;
    floatx4 a0, a1;
    if (more) {
      const long ktn = (long)(i + 1) << 5;
      if (ABF) {
        STAGE_AH(cur ^ 1, ktn);
      } else {
        const float* src = Af + (arow0 + arow) * (long)K + ktn + acseg * 8;
        a0 = *reinterpret_cast<const floatx4*>(src);
        a1 = *reinterpret_cast<const floatx4*>(src + 4);
      }
      STAGE_B(cur ^ 1, ktn);
    }

    shortx8 af[4], bf[4];
    #pragma unroll
    for (int rb = 0; rb < 4; ++rb) {
      int row = wr * 64 + rb * 16 + (lane & 15);
      af[rb] = *reinterpret_cast<const shortx8*>(
          &As[cur][row * 32 + (((lane >> 4) ^ ((row >> 1) & 3)) * 8)]);
    }
    #pragma unroll
    for (int cb = 0; cb < 4; ++cb) {
      int row = wc * 64 + cb * 16 + (lane & 15);
      bf[cb] = *reinterpret_cast<const shortx8*>(
          &Bs[cur][row * 32 + (((lane >> 4) ^ ((row >> 1) & 3)) * 8)]);
    }
    #pragma unroll
    for (int rb = 0; rb < 4; ++rb) {
      #pragma unroll
      for (int cb = 0; cb < 4; ++cb)
        acc[rb][cb] = __builtin_amdgcn_mfma_f32_16x16x32_bf16(
            af[rb], bf[cb], acc[rb][cb], 0, 0, 0);
    }

    if (more && !ABF)
      *reinterpret_cast<shortx8*>(&As[cur ^ 1][aswz]) = cvt8(a0, a1);
    __syncthreads();
  }
  #undef STAGE_B
  #undef STAGE_AH

  #pragma unroll
  for (int rb = 0; rb < 4; ++rb) {
    #pragma unroll
    for (int cb = 0; cb < 4; ++cb) {
      long gr0 = arow0 + wr * 64 + rb * 16 + (lane >> 4) * 4;
      long gc  = bcol0 + wc * 64 + cb * 16 + (lane & 15);
      if (MODE == 0) {
        float bv = bias[gc];
        #pragma unroll
        for (int r = 0; r < 4; ++r)
          ((float*)Cout)[(gr0 + r) * N + gc] = acc[rb][cb][r] + bv;
      } else if (MODE == 2) {
        long b = gr0 >> MBITS, m = gr0 & ((1 << MBITS) - 1);
        long h = gc >> 6, d = gc & 63;
        #pragma unroll
        for (int r = 0; r < 4; ++r)
          ((unsigned short*)Cout)[((((b * 8 + h) << MBITS) + m + r) << 6) + d] =
              f2bf(acc[rb][cb][r] * oscale);
      }
    }
  }
}

// Flash attention (R3 structure + setprio on MFMA clusters).
__global__ __launch_bounds__(256, 2)
void k_attn(const unsigned short* __restrict__ Qh,
            const unsigned short* __restrict__ Kh,
            const unsigned short* __restrict__ Vt,
            unsigned short* __restrict__ Aout) {
  __shared__ unsigned short Ks[64][72];
  __shared__ unsigned short Vs[64][72];
  __shared__ unsigned short QPs[64][72];
  const int tid = threadIdx.x;
  const int lane = tid & 63;
  const int w = tid >> 6;
  const int wg = blockIdx.x;
  const int bh = wg & 63;
  const int qt = wg >> 6;
  const int b = bh >> 3, h = bh & 7;

  const unsigned short* Qbase = Qh + (((long)bh << 9) + qt * 64) * 64;
  const unsigned short* Kbase = Kh + (((long)bh) << 18);
  const unsigned short* Vbase = Vt + (((long)bh) << 18);

  const int sr = tid >> 2;
  const int sc = (tid & 3) * 16;

  {
    const unsigned short* src = Qbase + sr * 64 + sc;
    *reinterpret_cast<shortx8*>(&QPs[sr][sc]) =
        *reinterpret_cast<const shortx8*>(src);
    *reinterpret_cast<shortx8*>(&QPs[sr][sc + 8]) =
        *reinterpret_cast<const shortx8*>(src + 8);
  }
  {
    const unsigned short* ksrc = Kbase + sr * 64 + sc;
    *reinterpret_cast<shortx8*>(&Ks[sr][sc]) =
        *reinterpret_cast<const shortx8*>(ksrc);
    *reinterpret_cast<shortx8*>(&Ks[sr][sc + 8]) =
        *reinterpret_cast<const shortx8*>(ksrc + 8);
    const unsigned short* vsrc = Vbase + ((long)sr << 12) + sc;
    *reinterpret_cast<shortx8*>(&Vs[sr][sc]) =
        *reinterpret_cast<const shortx8*>(vsrc);
    *reinterpret_cast<shortx8*>(&Vs[sr][sc + 8]) =
        *reinterpret_cast<const shortx8*>(vsrc + 8);
  }
  __syncthreads();

  shortx8 qf[2];
  qf[0] = *reinterpret_cast<const shortx8*>(
      &QPs[w * 16 + (lane & 15)][(lane >> 4) * 8]);
  qf[1] = *reinterpret_cast<const shortx8*>(
      &QPs[w * 16 + (lane & 15)][32 + (lane >> 4) * 8]);

  floatx4 o_acc[4] = {};
  float l_part[4] = {0.f, 0.f, 0.f, 0.f};
  shortx8 kpre[2], vpre[2];

  for (int mt = 0; mt < M_KV / 64; ++mt) {
    if (mt < M_KV / 64 - 1) {
      const unsigned short* ksrc = Kbase + ((mt + 1) * 64 + sr) * 64 + sc;
      kpre[0] = *reinterpret_cast<const shortx8*>(ksrc);
      kpre[1] = *reinterpret_cast<const shortx8*>(ksrc + 8);
      const unsigned short* vsrc = Vbase + ((long)sr << 12) + (mt + 1) * 64 + sc;
      vpre[0] = *reinterpret_cast<const shortx8*>(vsrc);
      vpre[1] = *reinterpret_cast<const shortx8*>(vsrc + 8);
    }

    floatx4 s[4];
    __builtin_amdgcn_s_setprio(1);
    #pragma unroll
    for (int cb = 0; cb < 4; ++cb) {
      shortx8 k0 = *reinterpret_cast<const shortx8*>(
          &Ks[cb * 16 + (lane & 15)][(lane >> 4) * 8]);
      shortx8 k1 = *reinterpret_cast<const shortx8*>(
          &Ks[cb * 16 + (lane & 15)][32 + (lane >> 4) * 8]);
      floatx4 z = {};
      z = __builtin_amdgcn_mfma_f32_16x16x32_bf16(qf[0], k0, z, 0, 0, 0);
      s[cb] = __builtin_amdgcn_mfma_f32_16x16x32_bf16(qf[1], k1, z, 0, 0, 0);
    }
    __builtin_amdgcn_s_setprio(0);

    #pragma unroll
    for (int cb = 0; cb < 4; ++cb) {
      #pragma unroll
      for (int r = 0; r < 4; ++r) {
        float pv = __expf(s[cb][r]);
        l_part[r] += pv;
        QPs[w * 16 + (lane >> 4) * 4 + r][cb * 16 + (lane & 15)] = f2bf(pv);
      }
    }

    __builtin_amdgcn_s_setprio(1);
    #pragma unroll
    for (int kk = 0; kk < 2; ++kk) {
      shortx8 pf = *reinterpret_cast<const shortx8*>(
          &QPs[w * 16 + (lane & 15)][kk * 32 + (lane >> 4) * 8]);
      #pragma unroll
      for (int db = 0; db < 4; ++db) {
        shortx8 vf = *reinterpret_cast<const shortx8*>(
            &Vs[db * 16 + (lane & 15)][kk * 32 + (lane >> 4) * 8]);
        o_acc[db] = __builtin_amdgcn_mfma_f32_16x16x32_bf16(
            pf, vf, o_acc[db], 0, 0, 0);
      }
    }
    __builtin_amdgcn_s_setprio(0);

    __syncthreads();
    if (mt < M_KV / 64 - 1) {
      *reinterpret_cast<shortx8*>(&Ks[sr][sc]) = kpre[0];
      *reinterpret_cast<shortx8*>(&Ks[sr][sc + 8]) = kpre[1];
      *reinterpret_cast<shortx8*>(&Vs[sr][sc]) = vpre[0];
      *reinterpret_cast<shortx8*>(&Vs[sr][sc + 8]) = vpre[1];
      __syncthreads();
    }
  }

  float inv[4];
  #pragma unroll
  for (int r = 0; r < 4; ++r) {
    float l = l_part[r];
    l += __shfl_xor(l, 1);
    l += __shfl_xor(l, 2);
    l += __shfl_xor(l, 4);
    l += __shfl_xor(l, 8);
    inv[r] = 1.f / l;
  }
  #pragma unroll
  for (int db = 0; db < 4; ++db) {
    #pragma unroll
    for (int r = 0; r < 4; ++r) {
      int n = qt * 64 + w * 16 + (lane >> 4) * 4 + r;
      long idx = ((long)(b * N_Q + n)) * INNER + h * HDIM + db * 16 + (lane & 15);
      Aout[idx] = f2bf(o_acc[db][r] * inv[r]);
    }
  }
}

extern "C" void kernel_launch(void* const* d_in, const int* in_sizes, int n_in,
                              void* d_out, int out_size, void* d_ws, size_t ws_size,
                              hipStream_t stream) {
  const float* x   = (const float*)d_in[0];
  const float* ctx = (const float*)d_in[1];
  const float* Wq  = (const float*)d_in[2];
  const float* Wk  = (const float*)d_in[3];
  const float* Wv  = (const float*)d_in[4];
  const float* Wo  = (const float*)d_in[5];
  const float* bo  = (const float*)d_in[6];
  float* out = (float*)d_out;

  char* ws = (char*)d_ws;
  unsigned short* Qh   = (unsigned short*)(ws);                    // 4MB
  unsigned short* Kh   = (unsigned short*)(ws + (4ull  << 20));    // 32MB
  unsigned short* Vt   = (unsigned short*)(ws + (36ull << 20));    // 32MB
  unsigned short* ctxh = (unsigned short*)(ws + (68ull << 20));    // 64MB
  unsigned short* Aat  = (unsigned short*)(ws + (68ull << 20));    // aliases ctxh
  unsigned short* Wqt  = (unsigned short*)(ws + (132ull << 20));   // 1MB
  unsigned short* Wkvt = (unsigned short*)(ws + (133ull << 20));   // 2MB
  unsigned short* Wot  = (unsigned short*)(ws + (135ull << 20));   // 1MB

  // ctx fp32 -> bf16 (single clean pass)
  k_cvt_bf16<<<dim3(2048), dim3(256), 0, stream>>>(
      ctx, ctxh, (long)B_SZ * M_KV * DIM);

  // all four weight transposes, one launch
  k_transpose_all<<<dim3(32, 32, 4), dim3(256), 0, stream>>>(
      Wq, Wk, Wv, Wo, Wqt, Wkvt, Wot);

  // Q projection (head-blocked bf16, pre-scaled 1/8)
  k_gemm<2, false, 2, 9><<<dim3(64), dim3(512), 0, stream>>>(
      x, Wqt, Qh, nullptr, B_SZ * N_Q, INNER, DIM, 0.125f);

  // fused K+V projection: 256x256, 4-buffer counted-vmcnt pipeline
  k_gemm_kv<<<dim3(512), dim3(512), 0, stream>>>(ctxh, Wkvt, Kh, Vt);

  k_attn<<<dim3(B_SZ * NHEADS * (N_Q / 64)), dim3(256), 0, stream>>>(Qh, Kh, Vt, Aat);

  // output projection (bf16 A) + bias, fp32 out
  k_gemm<0, true, 4, 0><<<dim3(128), dim3(512), 0, stream>>>(
      Aat, Wot, out, bo, B_SZ * N_Q, DIM, INNER, 1.0f);
}

// Round 10
// 259.058 us; speedup vs baseline: 1.0057x; 1.0057x over previous
//
#include <hip/hip_runtime.h>
#include <hip/hip_bf16.h>

#define B_SZ 8
#define N_Q 512
#define M_KV 4096
#define DIM 1024
#define INNER 512
#define NHEADS 8
#define HDIM 64

typedef __attribute__((ext_vector_type(4))) float floatx4;
typedef __attribute__((ext_vector_type(8))) short shortx8;
typedef __attribute__((ext_vector_type(4))) short shortx4;

__device__ inline unsigned short f2bf(float f) {
  union { float f; unsigned u; } x; x.f = f;
  unsigned r = x.u + 0x7FFFu + ((x.u >> 16) & 1u);
  return (unsigned short)(r >> 16);
}

__device__ inline shortx8 cvt8(floatx4 a, floatx4 b) {
  shortx8 h;
  h[0] = (short)f2bf(a[0]); h[1] = (short)f2bf(a[1]);
  h[2] = (short)f2bf(a[2]); h[3] = (short)f2bf(a[3]);
  h[4] = (short)f2bf(b[0]); h[5] = (short)f2bf(b[1]);
  h[6] = (short)f2bf(b[2]); h[7] = (short)f2bf(b[3]);
  return h;
}

__device__ inline void gload16(const void* g, void* l) {
  __builtin_amdgcn_global_load_lds(
      (const __attribute__((address_space(1))) void*)g,
      (__attribute__((address_space(3))) void*)l, 16, 0, 0);
}

// fp32 -> bf16 bulk convert (memory-bound, grid-stride)
__global__ void k_cvt_bf16(const float* __restrict__ src,
                           unsigned short* __restrict__ dst, long n) {
  long stride = (long)gridDim.x * 256 * 8;
  for (long i = ((long)blockIdx.x * 256 + threadIdx.x) * 8; i < n; i += stride) {
    floatx4 a = *reinterpret_cast<const floatx4*>(src + i);
    floatx4 b = *reinterpret_cast<const floatx4*>(src + i + 4);
    *reinterpret_cast<shortx8*>(dst + i) = cvt8(a, b);
  }
}

// All four weight transposes in ONE launch. z=0:Wq z=1:Wk z=2:Wv z=3:Wo.
__global__ void k_transpose_all(const float* __restrict__ Wq,
                                const float* __restrict__ Wk,
                                const float* __restrict__ Wv,
                                const float* __restrict__ Wo,
                                unsigned short* __restrict__ Wqt,
                                unsigned short* __restrict__ Wkvt,
                                unsigned short* __restrict__ Wot) {
  __shared__ unsigned short t[32][36];
  const int z = blockIdx.z;
  const float* W;
  unsigned short* Wt;
  int K, N;
  if (z == 0)      { W = Wq; Wt = Wqt;  K = 1024; N = 512; }
  else if (z == 1) { W = Wk; Wt = Wkvt; K = 1024; N = 512; }
  else if (z == 2) { W = Wv; Wt = Wkvt + (size_t)512 * 1024; K = 1024; N = 512; }
  else             { W = Wo; Wt = Wot;  K = 512;  N = 1024; }
  if ((int)blockIdx.x * 32 >= K || (int)blockIdx.y * 32 >= N) return;
  const int kt = blockIdx.x * 32, nt = blockIdx.y * 32;
  const int tr = threadIdx.x >> 3;
  const int tc = (threadIdx.x & 7) * 4;
  floatx4 v = *reinterpret_cast<const floatx4*>(&W[(long)(kt + tr) * N + nt + tc]);
  #pragma unroll
  for (int j = 0; j < 4; ++j) t[tr][tc + j] = f2bf(v[j]);
  __syncthreads();
  shortx4 o;
  #pragma unroll
  for (int j = 0; j < 4; ++j) o[j] = (short)t[tc + j][tr];
  *reinterpret_cast<shortx4*>(&Wt[(long)(nt + tr) * K + kt + tc]) = o;
}

// Fused K+V projection (R8 proven version): 128x128 tile, BK=32, 4 waves,
// A and B via global_load_lds w=16 (swizzled global src, linear LDS dest),
// dbuf, ONE __syncthreads per K-step, setprio on MFMA. 4 blocks/CU.
__global__ __launch_bounds__(256, 4)
void k_gemm_kv(const unsigned short* __restrict__ Ah,
               const unsigned short* __restrict__ Wkvt,
               unsigned short* __restrict__ Kh,
               unsigned short* __restrict__ Vt) {
  __shared__ unsigned short As[2][128 * 32];
  __shared__ unsigned short Bs[2][128 * 32];
  const int tid = threadIdx.x;
  const int lane = tid & 63;
  const int w = tid >> 6;
  const int wr = w >> 1, wc = w & 1;
  const int fr = lane & 15, fc = lane >> 4;

  const int L = ((blockIdx.x & 7) << 8) + (blockIdx.x >> 3);
  const int mt = L >> 3, nt = L & 7;
  const long arow0 = (long)mt << 7;
  const long bcol0 = (long)nt << 7;

  const int grow = lane >> 2;
  const int gpos = lane & 3;

  floatx4 acc[4][4] = {};

  #define STAGE(buf, kt)                                                      \
    {                                                                         \
      _Pragma("unroll")                                                       \
      for (int g = 0; g < 2; ++g) {                                           \
        const int rl = w * 32 + g * 16 + grow;                                \
        const int cc = gpos ^ ((rl >> 1) & 3);                                \
        gload16(Ah + (arow0 + rl) * 1024 + (kt) + cc * 8,                     \
                &As[buf][(w * 32 + g * 16) * 32]);                            \
        gload16(Wkvt + (bcol0 + rl) * 1024 + (kt) + cc * 8,                   \
                &Bs[buf][(w * 32 + g * 16) * 32]);                            \
      }                                                                       \
    }

  STAGE(0, 0);
  __syncthreads();

  for (int i = 0; i < 32; ++i) {
    const int cur = i & 1;
    if (i < 31) STAGE(cur ^ 1, (i + 1) << 5);

    shortx8 af[4], bf[4];
    #pragma unroll
    for (int rb = 0; rb < 4; ++rb) {
      int row = wr * 64 + rb * 16 + fr;
      af[rb] = *reinterpret_cast<const shortx8*>(
          &As[cur][row * 32 + ((fc ^ ((row >> 1) & 3)) * 8)]);
    }
    #pragma unroll
    for (int cb = 0; cb < 4; ++cb) {
      int row = wc * 64 + cb * 16 + fr;
      bf[cb] = *reinterpret_cast<const shortx8*>(
          &Bs[cur][row * 32 + ((fc ^ ((row >> 1) & 3)) * 8)]);
    }
    __builtin_amdgcn_s_setprio(1);
    #pragma unroll
    for (int rb = 0; rb < 4; ++rb) {
      #pragma unroll
      for (int cb = 0; cb < 4; ++cb)
        acc[rb][cb] = __builtin_amdgcn_mfma_f32_16x16x32_bf16(
            af[rb], bf[cb], acc[rb][cb], 0, 0, 0);
    }
    __builtin_amdgcn_s_setprio(0);
    __syncthreads();
  }
  #undef STAGE

  #pragma unroll
  for (int rb = 0; rb < 4; ++rb) {
    #pragma unroll
    for (int cb = 0; cb < 4; ++cb) {
      long gr0 = arow0 + wr * 64 + rb * 16 + fc * 4;
      long gc = bcol0 + wc * 64 + cb * 16 + fr;
      long b = gr0 >> 12, m = gr0 & 4095;
      if (gc < 512) {
        long h = gc >> 6, d = gc & 63;
        #pragma unroll
        for (int r = 0; r < 4; ++r)
          Kh[((((b * 8 + h) << 12) + m + r) << 6) + d] = f2bf(acc[rb][cb][r]);
      } else {
        long h = (gc - 512) >> 6, d = (gc - 512) & 63;
        shortx4 hv;
        #pragma unroll
        for (int r = 0; r < 4; ++r) hv[r] = (short)f2bf(acc[rb][cb][r]);
        *reinterpret_cast<shortx4*>(&Vt[(((b * 8 + h) * 64 + d) << 12) + m]) = hv;
      }
    }
  }
}

// General GEMM (Q-projection, out-projection), unchanged.
template<int MODE, bool ABF, int NCOL, int MBITS>
__global__ __launch_bounds__(512, 4)
void k_gemm(const void* __restrict__ Ap, const unsigned short* __restrict__ Bt,
            void* __restrict__ Cout, const float* __restrict__ bias,
            int M, int N, int K, float oscale) {
  __shared__ unsigned short As[2][128 * 32];
  __shared__ unsigned short Bs[2][256 * 32];
  const int tid = threadIdx.x;
  const int lane = tid & 63;
  const int w = tid >> 6;
  const int wr = w >> 2, wc = w & 3;

  const int cpx = gridDim.x >> 3;
  const int L = (blockIdx.x & 7) * cpx + (blockIdx.x >> 3);
  const long arow0 = (long)(L / NCOL) * 128;
  const long bcol0 = (long)(L % NCOL) * 256;

  const float* Af = (const float*)Ap;
  const unsigned short* Ah = (const unsigned short*)Ap;

  const int lsub = lane >> 2;
  const int lchunk = (lane & 3) ^ ((lane >> 3) & 3);
  const long brow0 = bcol0 + (w * 2 + 0) * 16 + lsub;
  const long brow1 = bcol0 + (w * 2 + 1) * 16 + lsub;
  const long ahrow = arow0 + w * 16 + lsub;
  const int arow = tid >> 2;
  const int acseg = tid & 3;
  const int aswz = arow * 32 + ((acseg ^ ((arow >> 1) & 3)) * 8);

  floatx4 acc[4][4] = {};

  #define STAGE_B(buf, kt)                                                   \
    {                                                                        \
      gload16(Bt + brow0 * K + (kt) + lchunk * 8, &Bs[buf][(w * 2) * 512]);  \
      gload16(Bt + brow1 * K + (kt) + lchunk * 8,                            \
              &Bs[buf][(w * 2 + 1) * 512]);                                  \
    }
  #define STAGE_AH(buf, kt) \
    gload16(Ah + ahrow * K + (kt) + lchunk * 8, &As[buf][w * 512]);

  if (ABF) {
    STAGE_AH(0, 0);
  } else {
    const float* src = Af + (arow0 + arow) * (long)K + acseg * 8;
    floatx4 a0 = *reinterpret_cast<const floatx4*>(src);
    floatx4 a1 = *reinterpret_cast<const floatx4*>(src + 4);
    *reinterpret_cast<shortx8*>(&As[0][aswz]) = cvt8(a0, a1);
  }
  STAGE_B(0, 0);
  __syncthreads();

  const int NK = K >> 5;
  for (int i = 0; i < NK; ++i) {
    const int cur = i & 1;
    const bool more = (i + 1) < NK;
    floatx4 a0, a1;
    if (more) {
      const long ktn = (long)(i + 1) << 5;
      if (ABF) {
        STAGE_AH(cur ^ 1, ktn);
      } else {
        const float* src = Af + (arow0 + arow) * (long)K + ktn + acseg * 8;
        a0 = *reinterpret_cast<const floatx4*>(src);
        a1 = *reinterpret_cast<const floatx4*>(src + 4);
      }
      STAGE_B(cur ^ 1, ktn);
    }

    shortx8 af[4], bf[4];
    #pragma unroll
    for (int rb = 0; rb < 4; ++rb) {
      int row = wr * 64 + rb * 16 + (lane & 15);
      af[rb] = *reinterpret_cast<const shortx8*>(
          &As[cur][row * 32 + (((lane >> 4) ^ ((row >> 1) & 3)) * 8)]);
    }
    #pragma unroll
    for (int cb = 0; cb < 4; ++cb) {
      int row = wc * 64 + cb * 16 + (lane & 15);
      bf[cb] = *reinterpret_cast<const shortx8*>(
          &Bs[cur][row * 32 + (((lane >> 4) ^ ((row >> 1) & 3)) * 8)]);
    }
    #pragma unroll
    for (int rb = 0; rb < 4; ++rb) {
      #pragma unroll
      for (int cb = 0; cb < 4; ++cb)
        acc[rb][cb] = __builtin_amdgcn_mfma_f32_16x16x32_bf16(
            af[rb], bf[cb], acc[rb][cb], 0, 0, 0);
    }

    if (more && !ABF)
      *reinterpret_cast<shortx8*>(&As[cur ^ 1][aswz]) = cvt8(a0, a1);
    __syncthreads();
  }
  #undef STAGE_B
  #undef STAGE_AH

  #pragma unroll
  for (int rb = 0; rb < 4; ++rb) {
    #pragma unroll
    for (int cb = 0; cb < 4; ++cb) {
      long gr0 = arow0 + wr * 64 + rb * 16 + (lane >> 4) * 4;
      long gc  = bcol0 + wc * 64 + cb * 16 + (lane & 15);
      if (MODE == 0) {
        float bv = bias[gc];
        #pragma unroll
        for (int r = 0; r < 4; ++r)
          ((float*)Cout)[(gr0 + r) * N + gc] = acc[rb][cb][r] + bv;
      } else if (MODE == 2) {
        long b = gr0 >> MBITS, m = gr0 & ((1 << MBITS) - 1);
        long h = gc >> 6, d = gc & 63;
        #pragma unroll
        for (int r = 0; r < 4; ++r)
          ((unsigned short*)Cout)[((((b * 8 + h) << MBITS) + m + r) << 6) + d] =
              f2bf(acc[rb][cb][r] * oscale);
      }
    }
  }
}

// Flash attention, KV-split x2, gload_lds-staged double-buffered K/V.
// Block = (split, qt, bh); 4 waves x 16 Q-rows. One barrier per KV tile.
// Writes unnormalized O (fp32) + l to ws; k_attn_reduce combines.
__global__ __launch_bounds__(256, 3)
void k_attn(const unsigned short* __restrict__ Qh,
            const unsigned short* __restrict__ Kh,
            const unsigned short* __restrict__ Vt,
            float* __restrict__ Opart, float* __restrict__ Lpart) {
  __shared__ unsigned short Qs[64 * 64];
  __shared__ unsigned short Ks[2][64 * 64];
  __shared__ unsigned short Vs[2][64 * 64];
  __shared__ unsigned short Ps[64][72];
  const int tid = threadIdx.x;
  const int lane = tid & 63;
  const int w = tid >> 6;
  const int wg = blockIdx.x;      // sp*512 + qt*64 + bh
  const int bh = wg & 63;         // XCD = wg%8 = bh%8: K/V L2-shared
  const int qt = (wg >> 6) & 7;
  const int sp = wg >> 9;         // 0/1: KV halves
  const int fr = lane & 15, fc = lane >> 4;

  const unsigned short* Qbase = Qh + (((long)bh << 9) + qt * 64) * 64;
  const unsigned short* Kbase = Kh + (((long)bh) << 18);
  const unsigned short* Vbase = Vt + (((long)bh) << 18);

  // gload lane geometry: 8 rows/issue; row = base+(l>>3), pos = l&7,
  // fetched chunk c = pos ^ (row&7)  (16B chunks in 128B rows)
  const int grow = lane >> 3;
  const int gpos = lane & 7;

  #define STAGE_KV(buf, mt_)                                              \
    { _Pragma("unroll")                                                   \
      for (int j = 0; j < 2; ++j) {                                       \
        const int r = w * 16 + j * 8 + grow;                              \
        const int c = gpos ^ (r & 7);                                     \
        gload16(Kbase + ((mt_) * 64 + r) * 64 + c * 8,                    \
                &Ks[buf][(w * 16 + j * 8) * 64]);                         \
        gload16(Vbase + (((long)r) << 12) + (mt_) * 64 + c * 8,           \
                &Vs[buf][(w * 16 + j * 8) * 64]);                         \
      } }

  const int mt0 = sp * 32;
  {
    #pragma unroll
    for (int j = 0; j < 2; ++j) {
      const int r = w * 16 + j * 8 + grow;
      const int c = gpos ^ (r & 7);
      gload16(Qbase + r * 64 + c * 8, &Qs[(w * 16 + j * 8) * 64]);
    }
    STAGE_KV(0, mt0);
  }
  __syncthreads();

  shortx8 qf[2];
  #pragma unroll
  for (int kk = 0; kk < 2; ++kk)
    qf[kk] = *reinterpret_cast<const shortx8*>(
        &Qs[(w * 16 + fr) * 64 + (((kk * 4 + fc) ^ (fr & 7)) * 8)]);

  floatx4 o_acc[4] = {};
  float l_part[4] = {0.f, 0.f, 0.f, 0.f};

  for (int it = 0; it < 32; ++it) {
    const int cur = it & 1;
    if (it < 31) STAGE_KV(cur ^ 1, mt0 + it + 1);

    floatx4 s[4];
    __builtin_amdgcn_s_setprio(1);
    #pragma unroll
    for (int cb = 0; cb < 4; ++cb) {
      int row = cb * 16 + fr;
      shortx8 k0 = *reinterpret_cast<const shortx8*>(
          &Ks[cur][row * 64 + ((fc ^ (fr & 7)) * 8)]);
      shortx8 k1 = *reinterpret_cast<const shortx8*>(
          &Ks[cur][row * 64 + (((4 + fc) ^ (fr & 7)) * 8)]);
      floatx4 z = {};
      z = __builtin_amdgcn_mfma_f32_16x16x32_bf16(qf[0], k0, z, 0, 0, 0);
      s[cb] = __builtin_amdgcn_mfma_f32_16x16x32_bf16(qf[1], k1, z, 0, 0, 0);
    }
    __builtin_amdgcn_s_setprio(0);

    #pragma unroll
    for (int cb = 0; cb < 4; ++cb) {
      #pragma unroll
      for (int r = 0; r < 4; ++r) {
        float pv = __expf(s[cb][r]);
        l_part[r] += pv;
        Ps[w * 16 + fc * 4 + r][cb * 16 + fr] = f2bf(pv);
      }
    }

    __builtin_amdgcn_s_setprio(1);
    #pragma unroll
    for (int kk = 0; kk < 2; ++kk) {
      shortx8 pf = *reinterpret_cast<const shortx8*>(
          &Ps[w * 16 + fr][kk * 32 + fc * 8]);
      #pragma unroll
      for (int db = 0; db < 4; ++db) {
        int row = db * 16 + fr;
        shortx8 vf = *reinterpret_cast<const shortx8*>(
            &Vs[cur][row * 64 + (((kk * 4 + fc) ^ (fr & 7)) * 8)]);
        o_acc[db] = __builtin_amdgcn_mfma_f32_16x16x32_bf16(
            pf, vf, o_acc[db], 0, 0, 0);
      }
    }
    __builtin_amdgcn_s_setprio(0);
    __syncthreads();  // drains gloads; reads of buf[cur] done
  }
  #undef STAGE_KV

  // reduce l over the 16-lane row group; store unnormalized O + l
  #pragma unroll
  for (int r = 0; r < 4; ++r) {
    float l = l_part[r];
    l += __shfl_xor(l, 1);
    l += __shfl_xor(l, 2);
    l += __shfl_xor(l, 4);
    l += __shfl_xor(l, 8);
    l_part[r] = l;
  }
  float* Ob = Opart + (long)wg * 4096;
  #pragma unroll
  for (int db = 0; db < 4; ++db) {
    #pragma unroll
    for (int r = 0; r < 4; ++r)
      Ob[(w * 16 + fc * 4 + r) * 64 + db * 16 + fr] = o_acc[db][r];
  }
  if (fr == 0) {
    #pragma unroll
    for (int r = 0; r < 4; ++r)
      Lpart[(long)wg * 64 + w * 16 + fc * 4 + r] = l_part[r];
  }
}

// Combine the two KV-splits: Aat[b][n][h*64+d] = (O0+O1)/(l0+l1), bf16.
__global__ void k_attn_reduce(const float* __restrict__ Opart,
                              const float* __restrict__ Lpart,
                              unsigned short* __restrict__ Aat) {
  const int tid = threadIdx.x;
  const int g = blockIdx.x * 4 + (tid >> 6);  // global row, 0..32767
  const int d = tid & 63;
  const int bh = g >> 9, n = g & 511;
  const int b = bh >> 3, h = bh & 7;
  const int qt = n >> 6, rr = n & 63;
  const long i0 = ((long)(qt * 64 + bh)) * 4096 + rr * 64 + d;
  const long i1 = ((long)(512 + qt * 64 + bh)) * 4096 + rr * 64 + d;
  const float l = Lpart[(long)(qt * 64 + bh) * 64 + rr] +
                  Lpart[(long)(512 + qt * 64 + bh) * 64 + rr];
  const float o = Opart[i0] + Opart[i1];
  Aat[((long)(b * 512 + n)) * 512 + h * 64 + d] = f2bf(o / l);
}

extern "C" void kernel_launch(void* const* d_in, const int* in_sizes, int n_in,
                              void* d_out, int out_size, void* d_ws, size_t ws_size,
                              hipStream_t stream) {
  const float* x   = (const float*)d_in[0];
  const float* ctx = (const float*)d_in[1];
  const float* Wq  = (const float*)d_in[2];
  const float* Wk  = (const float*)d_in[3];
  const float* Wv  = (const float*)d_in[4];
  const float* Wo  = (const float*)d_in[5];
  const float* bo  = (const float*)d_in[6];
  float* out = (float*)d_out;

  char* ws = (char*)d_ws;
  unsigned short* Qh   = (unsigned short*)(ws);                    // 4MB
  unsigned short* Kh   = (unsigned short*)(ws + (4ull  << 20));    // 32MB
  unsigned short* Vt   = (unsigned short*)(ws + (36ull << 20));    // 32MB
  unsigned short* ctxh = (unsigned short*)(ws + (68ull << 20));    // 64MB
  unsigned short* Aat  = (unsigned short*)(ws + (68ull << 20));    // 4MB, aliases ctxh (dead after KV)
  float*          Opart= (float*)         (ws + (76ull << 20));    // 16MB, inside dead ctxh
  float*          Lpart= (float*)         (ws + (92ull << 20));    // 256KB
  unsigned short* Wqt  = (unsigned short*)(ws + (132ull << 20));   // 1MB
  unsigned short* Wkvt = (unsigned short*)(ws + (133ull << 20));   // 2MB
  unsigned short* Wot  = (unsigned short*)(ws + (135ull << 20));   // 1MB

  k_cvt_bf16<<<dim3(2048), dim3(256), 0, stream>>>(
      ctx, ctxh, (long)B_SZ * M_KV * DIM);

  k_transpose_all<<<dim3(32, 32, 4), dim3(256), 0, stream>>>(
      Wq, Wk, Wv, Wo, Wqt, Wkvt, Wot);

  // Q projection (head-blocked bf16, pre-scaled 1/8)
  k_gemm<2, false, 2, 9><<<dim3(64), dim3(512), 0, stream>>>(
      x, Wqt, Qh, nullptr, B_SZ * N_Q, INNER, DIM, 0.125f);

  // fused K+V projection (R8 proven, 2048 blocks)
  k_gemm_kv<<<dim3(2048), dim3(256), 0, stream>>>(ctxh, Wkvt, Kh, Vt);

  // attention: 1024 blocks (2 KV-splits), then combine
  k_attn<<<dim3(1024), dim3(256), 0, stream>>>(Qh, Kh, Vt, Opart, Lpart);
  k_attn_reduce<<<dim3(8192), dim3(256), 0, stream>>>(Opart, Lpart, Aat);

  // output projection (bf16 A) + bias, fp32 out
  k_gemm<0, true, 4, 0><<<dim3(128), dim3(512), 0, stream>>>(
      Aat, Wot, out, bo, B_SZ * N_Q, DIM, INNER, 1.0f);
}

// Round 11
// 244.428 us; speedup vs baseline: 1.0659x; 1.0599x over previous
//
#include <hip/hip_runtime.h>
#include <hip/hip_bf16.h>

#define B_SZ 8
#define N_Q 512
#define M_KV 4096
#define DIM 1024
#define INNER 512
#define NHEADS 8
#define HDIM 64

typedef __attribute__((ext_vector_type(4))) float floatx4;
typedef __attribute__((ext_vector_type(8))) short shortx8;
typedef __attribute__((ext_vector_type(4))) short shortx4;

#define QSCALE 0.18033688011112042f  /* 0.125 * log2(e): attn uses exp2 */

__device__ inline unsigned short f2bf(float f) {
  union { float f; unsigned u; } x; x.f = f;
  unsigned r = x.u + 0x7FFFu + ((x.u >> 16) & 1u);
  return (unsigned short)(r >> 16);
}

__device__ inline shortx8 cvt8(floatx4 a, floatx4 b) {
  shortx8 h;
  h[0] = (short)f2bf(a[0]); h[1] = (short)f2bf(a[1]);
  h[2] = (short)f2bf(a[2]); h[3] = (short)f2bf(a[3]);
  h[4] = (short)f2bf(b[0]); h[5] = (short)f2bf(b[1]);
  h[6] = (short)f2bf(b[2]); h[7] = (short)f2bf(b[3]);
  return h;
}

__device__ inline void gload16(const void* g, void* l) {
  __builtin_amdgcn_global_load_lds(
      (const __attribute__((address_space(1))) void*)g,
      (__attribute__((address_space(3))) void*)l, 16, 0, 0);
}

// fp32 -> bf16 bulk convert (memory-bound, grid-stride)
__global__ void k_cvt_bf16(const float* __restrict__ src,
                           unsigned short* __restrict__ dst, long n) {
  long stride = (long)gridDim.x * 256 * 8;
  for (long i = ((long)blockIdx.x * 256 + threadIdx.x) * 8; i < n; i += stride) {
    floatx4 a = *reinterpret_cast<const floatx4*>(src + i);
    floatx4 b = *reinterpret_cast<const floatx4*>(src + i + 4);
    *reinterpret_cast<shortx8*>(dst + i) = cvt8(a, b);
  }
}

// All four weight transposes in ONE launch. z=0:Wq z=1:Wk z=2:Wv z=3:Wo.
__global__ void k_transpose_all(const float* __restrict__ Wq,
                                const float* __restrict__ Wk,
                                const float* __restrict__ Wv,
                                const float* __restrict__ Wo,
                                unsigned short* __restrict__ Wqt,
                                unsigned short* __restrict__ Wkvt,
                                unsigned short* __restrict__ Wot) {
  __shared__ unsigned short t[32][36];
  const int z = blockIdx.z;
  const float* W;
  unsigned short* Wt;
  int K, N;
  if (z == 0)      { W = Wq; Wt = Wqt;  K = 1024; N = 512; }
  else if (z == 1) { W = Wk; Wt = Wkvt; K = 1024; N = 512; }
  else if (z == 2) { W = Wv; Wt = Wkvt + (size_t)512 * 1024; K = 1024; N = 512; }
  else             { W = Wo; Wt = Wot;  K = 512;  N = 1024; }
  if ((int)blockIdx.x * 32 >= K || (int)blockIdx.y * 32 >= N) return;
  const int kt = blockIdx.x * 32, nt = blockIdx.y * 32;
  const int tr = threadIdx.x >> 3;
  const int tc = (threadIdx.x & 7) * 4;
  floatx4 v = *reinterpret_cast<const floatx4*>(&W[(long)(kt + tr) * N + nt + tc]);
  #pragma unroll
  for (int j = 0; j < 4; ++j) t[tr][tc + j] = f2bf(v[j]);
  __syncthreads();
  shortx4 o;
  #pragma unroll
  for (int j = 0; j < 4; ++j) o[j] = (short)t[tc + j][tr];
  *reinterpret_cast<shortx4*>(&Wt[(long)(nt + tr) * K + kt + tc]) = o;
}

// Combined projection: blocks <2048 do fused K+V (A=ctxh bf16 via gload),
// blocks >=2048 do Q projection (A=x fp32 reg-staged, scale folded w/ log2e).
// Proven R8 body: 128x128 tile, BK=32, 4 waves, dbuf, one barrier/K-step.
__global__ __launch_bounds__(256, 4)
void k_proj(const unsigned short* __restrict__ ctxh,
            const float* __restrict__ x,
            const unsigned short* __restrict__ Wkvt,
            const unsigned short* __restrict__ Wqt,
            unsigned short* __restrict__ Kh,
            unsigned short* __restrict__ Vt,
            unsigned short* __restrict__ Qh) {
  __shared__ unsigned short As[2][4096];
  __shared__ unsigned short Bs[2][4096];
  const int tid = threadIdx.x;
  const int lane = tid & 63;
  const int w = tid >> 6;
  const int wr = w >> 1, wc = w & 1;
  const int fr = lane & 15, fc = lane >> 4;
  const bool isQ = (int)blockIdx.x >= 2048;

  long arow0, bcol0;
  const unsigned short* Bb;
  if (!isQ) {
    const int L = ((blockIdx.x & 7) << 8) + (blockIdx.x >> 3);
    arow0 = (long)(L >> 3) << 7;
    bcol0 = (long)(L & 7) << 7;
    Bb = Wkvt;
  } else {
    const int t = blockIdx.x - 2048;
    arow0 = (long)(t >> 2) << 7;
    bcol0 = (long)(t & 3) << 7;
    Bb = Wqt;
  }

  const int grow = lane >> 2;
  const int gpos = lane & 3;
  // fp32 A staging (Q path): thread -> row tid>>1, k-half tid&1
  const int arw = tid >> 1;
  const int ahalf = tid & 1;
  const int aswz = (arw >> 1) & 3;
  const int as0 = ((2 * ahalf) ^ aswz) * 8;
  const int as1 = ((2 * ahalf + 1) ^ aswz) * 8;

  floatx4 acc[4][4] = {};

  #define STAGE_A(buf, kt)                                                    \
    { _Pragma("unroll")                                                       \
      for (int g = 0; g < 2; ++g) {                                           \
        const int rl = w * 32 + g * 16 + grow;                                \
        const int cc = gpos ^ ((rl >> 1) & 3);                                \
        gload16(ctxh + (arow0 + rl) * 1024 + (kt) + cc * 8,                   \
                &As[buf][(w * 32 + g * 16) * 32]);                            \
      } }
  #define STAGE_B(buf, kt)                                                    \
    { _Pragma("unroll")                                                       \
      for (int g = 0; g < 2; ++g) {                                           \
        const int rl = w * 32 + g * 16 + grow;                                \
        const int cc = gpos ^ ((rl >> 1) & 3);                                \
        gload16(Bb + (bcol0 + rl) * 1024 + (kt) + cc * 8,                     \
                &Bs[buf][(w * 32 + g * 16) * 32]);                            \
      } }

  // prologue
  if (!isQ) {
    STAGE_A(0, 0);
    STAGE_B(0, 0);
  } else {
    const float* s = x + (arow0 + arw) * 1024 + ahalf * 16;
    floatx4 a0 = *reinterpret_cast<const floatx4*>(s);
    floatx4 a1 = *reinterpret_cast<const floatx4*>(s + 4);
    floatx4 a2 = *reinterpret_cast<const floatx4*>(s + 8);
    floatx4 a3 = *reinterpret_cast<const floatx4*>(s + 12);
    STAGE_B(0, 0);
    *reinterpret_cast<shortx8*>(&As[0][arw * 32 + as0]) = cvt8(a0, a1);
    *reinterpret_cast<shortx8*>(&As[0][arw * 32 + as1]) = cvt8(a2, a3);
  }
  __syncthreads();

  for (int i = 0; i < 32; ++i) {
    const int cur = i & 1;
    const bool more = i < 31;
    floatx4 a0, a1, a2, a3;
    if (more) {
      const int ktn = (i + 1) << 5;
      if (!isQ) {
        STAGE_A(cur ^ 1, ktn);
        STAGE_B(cur ^ 1, ktn);
      } else {
        const float* s = x + (arow0 + arw) * 1024 + ktn + ahalf * 16;
        a0 = *reinterpret_cast<const floatx4*>(s);
        a1 = *reinterpret_cast<const floatx4*>(s + 4);
        a2 = *reinterpret_cast<const floatx4*>(s + 8);
        a3 = *reinterpret_cast<const floatx4*>(s + 12);
        STAGE_B(cur ^ 1, ktn);
      }
    }

    shortx8 af[4], bf[4];
    #pragma unroll
    for (int rb = 0; rb < 4; ++rb) {
      int row = wr * 64 + rb * 16 + fr;
      af[rb] = *reinterpret_cast<const shortx8*>(
          &As[cur][row * 32 + ((fc ^ ((row >> 1) & 3)) * 8)]);
    }
    #pragma unroll
    for (int cb = 0; cb < 4; ++cb) {
      int row = wc * 64 + cb * 16 + fr;
      bf[cb] = *reinterpret_cast<const shortx8*>(
          &Bs[cur][row * 32 + ((fc ^ ((row >> 1) & 3)) * 8)]);
    }
    __builtin_amdgcn_s_setprio(1);
    #pragma unroll
    for (int rb = 0; rb < 4; ++rb) {
      #pragma unroll
      for (int cb = 0; cb < 4; ++cb)
        acc[rb][cb] = __builtin_amdgcn_mfma_f32_16x16x32_bf16(
            af[rb], bf[cb], acc[rb][cb], 0, 0, 0);
    }
    __builtin_amdgcn_s_setprio(0);

    if (more && isQ) {
      *reinterpret_cast<shortx8*>(&As[cur ^ 1][arw * 32 + as0]) = cvt8(a0, a1);
      *reinterpret_cast<shortx8*>(&As[cur ^ 1][arw * 32 + as1]) = cvt8(a2, a3);
    }
    __syncthreads();
  }
  #undef STAGE_A
  #undef STAGE_B

  // epilogue
  #pragma unroll
  for (int rb = 0; rb < 4; ++rb) {
    #pragma unroll
    for (int cb = 0; cb < 4; ++cb) {
      long gr0 = arow0 + wr * 64 + rb * 16 + fc * 4;
      long gc = bcol0 + wc * 64 + cb * 16 + fr;
      if (!isQ) {
        long b = gr0 >> 12, m = gr0 & 4095;
        if (gc < 512) {
          long h = gc >> 6, d = gc & 63;
          #pragma unroll
          for (int r = 0; r < 4; ++r)
            Kh[((((b * 8 + h) << 12) + m + r) << 6) + d] = f2bf(acc[rb][cb][r]);
        } else {
          long h = (gc - 512) >> 6, d = (gc - 512) & 63;
          shortx4 hv;
          #pragma unroll
          for (int r = 0; r < 4; ++r) hv[r] = (short)f2bf(acc[rb][cb][r]);
          *reinterpret_cast<shortx4*>(&Vt[(((b * 8 + h) * 64 + d) << 12) + m]) = hv;
        }
      } else {
        long b = gr0 >> 9, m = gr0 & 511;
        long h = gc >> 6, d = gc & 63;
        #pragma unroll
        for (int r = 0; r < 4; ++r)
          Qh[((((b * 8 + h) << 9) + m + r) << 6) + d] =
              f2bf(acc[rb][cb][r] * QSCALE);
      }
    }
  }
}

// Output projection on the same proven body: A=Aat bf16 [4096][512] via
// gload, B=Wot [1024][512], K=512, fp32 out + bias. 256 blocks, 4/CU.
__global__ __launch_bounds__(256, 4)
void k_out(const unsigned short* __restrict__ Aat,
           const unsigned short* __restrict__ Wot,
           float* __restrict__ out, const float* __restrict__ bias) {
  __shared__ unsigned short As[2][4096];
  __shared__ unsigned short Bs[2][4096];
  const int tid = threadIdx.x;
  const int lane = tid & 63;
  const int w = tid >> 6;
  const int wr = w >> 1, wc = w & 1;
  const int fr = lane & 15, fc = lane >> 4;

  const int L = ((blockIdx.x & 7) << 5) + (blockIdx.x >> 3);
  const long arow0 = (long)(L >> 3) << 7;   // 0..31 -> rows
  const long bcol0 = (long)(L & 7) << 7;    // 0..7  -> cols

  const int grow = lane >> 2;
  const int gpos = lane & 3;

  floatx4 acc[4][4] = {};

  #define STAGE2(buf, kt)                                                     \
    { _Pragma("unroll")                                                       \
      for (int g = 0; g < 2; ++g) {                                           \
        const int rl = w * 32 + g * 16 + grow;                                \
        const int cc = gpos ^ ((rl >> 1) & 3);                                \
        gload16(Aat + (arow0 + rl) * 512 + (kt) + cc * 8,                     \
                &As[buf][(w * 32 + g * 16) * 32]);                            \
        gload16(Wot + (bcol0 + rl) * 512 + (kt) + cc * 8,                     \
                &Bs[buf][(w * 32 + g * 16) * 32]);                            \
      } }

  STAGE2(0, 0);
  __syncthreads();

  for (int i = 0; i < 16; ++i) {
    const int cur = i & 1;
    if (i < 15) STAGE2(cur ^ 1, (i + 1) << 5);

    shortx8 af[4], bf[4];
    #pragma unroll
    for (int rb = 0; rb < 4; ++rb) {
      int row = wr * 64 + rb * 16 + fr;
      af[rb] = *reinterpret_cast<const shortx8*>(
          &As[cur][row * 32 + ((fc ^ ((row >> 1) & 3)) * 8)]);
    }
    #pragma unroll
    for (int cb = 0; cb < 4; ++cb) {
      int row = wc * 64 + cb * 16 + fr;
      bf[cb] = *reinterpret_cast<const shortx8*>(
          &Bs[cur][row * 32 + ((fc ^ ((row >> 1) & 3)) * 8)]);
    }
    __builtin_amdgcn_s_setprio(1);
    #pragma unroll
    for (int rb = 0; rb < 4; ++rb) {
      #pragma unroll
      for (int cb = 0; cb < 4; ++cb)
        acc[rb][cb] = __builtin_amdgcn_mfma_f32_16x16x32_bf16(
            af[rb], bf[cb], acc[rb][cb], 0, 0, 0);
    }
    __builtin_amdgcn_s_setprio(0);
    __syncthreads();
  }
  #undef STAGE2

  #pragma unroll
  for (int rb = 0; rb < 4; ++rb) {
    #pragma unroll
    for (int cb = 0; cb < 4; ++cb) {
      long gr0 = arow0 + wr * 64 + rb * 16 + fc * 4;
      long gc = bcol0 + wc * 64 + cb * 16 + fr;
      float bv = bias[gc];
      #pragma unroll
      for (int r = 0; r < 4; ++r)
        out[(gr0 + r) * 1024 + gc] = acc[rb][cb][r] + bv;
    }
  }
}

// Flash attention, wave-tile 32x64 (32 MFMA per 20 LDS b128 reads), sp=4
// KV-splits, gload-staged dbuf K/V, exp2 (scale folded into Q).
// Block = 128 Q rows x 1024 KV rows. Ps aliases dead Q staging.
__global__ __launch_bounds__(256, 3)
void k_attn(const unsigned short* __restrict__ Qh,
            const unsigned short* __restrict__ Kh,
            const unsigned short* __restrict__ Vt,
            float* __restrict__ Opart, float* __restrict__ Lpart) {
  __shared__ unsigned short Ks[2][64 * 64];
  __shared__ unsigned short Vs[2][64 * 64];
  __shared__ unsigned short QPs[128 * 72];  // Q staged linear [128*64]; P as [128][72]
  const int tid = threadIdx.x;
  const int lane = tid & 63;
  const int w = tid >> 6;
  const int wg = blockIdx.x;          // (sp*4 + qt)*64 + bh
  const int bh = wg & 63;             // XCD = bh%8 -> K/V L2 shared
  const int qt = (wg >> 6) & 3;
  const int sp = wg >> 8;
  const int fr = lane & 15, fc = lane >> 4;

  const unsigned short* Qbase = Qh + (((long)bh << 9) + qt * 128) * 64;
  const unsigned short* Kbase = Kh + (((long)bh) << 18);
  const unsigned short* Vbase = Vt + (((long)bh) << 18);

  const int grow = lane >> 3;   // 0..7
  const int gpos = lane & 7;    // 16B slot in 128B row

  #define STAGE_KV(buf, mt_)                                              \
    { _Pragma("unroll")                                                   \
      for (int j = 0; j < 2; ++j) {                                       \
        const int r = w * 16 + j * 8 + grow;                              \
        const int c = gpos ^ (r & 7);                                     \
        gload16(Kbase + ((mt_) * 64 + r) * 64 + c * 8,                    \
                &Ks[buf][(w * 16 + j * 8) * 64]);                         \
        gload16(Vbase + (((long)r) << 12) + (mt_) * 64 + c * 8,           \
                &Vs[buf][(w * 16 + j * 8) * 64]);                         \
      } }

  const int mt0 = sp * 16;
  {
    #pragma unroll
    for (int j = 0; j < 4; ++j) {
      const int r = w * 32 + j * 8 + grow;
      const int c = gpos ^ (r & 7);
      gload16(Qbase + r * 64 + c * 8, &QPs[(w * 32 + j * 8) * 64]);
    }
    STAGE_KV(0, mt0);
  }
  __syncthreads();

  shortx8 qf[2][2];
  #pragma unroll
  for (int rf = 0; rf < 2; ++rf) {
    const int row = w * 32 + rf * 16 + fr;
    #pragma unroll
    for (int kk = 0; kk < 2; ++kk)
      qf[rf][kk] = *reinterpret_cast<const shortx8*>(
          &QPs[row * 64 + (((kk * 4 + fc) ^ (row & 7)) * 8)]);
  }
  __syncthreads();  // all Q reads done before P overwrites the buffer

  floatx4 o_acc[2][4] = {};
  float l_part[2][4] = {};

  for (int it = 0; it < 16; ++it) {
    const int cur = it & 1;
    if (it < 15) STAGE_KV(cur ^ 1, mt0 + it + 1);

    floatx4 s[2][4];
    __builtin_amdgcn_s_setprio(1);
    #pragma unroll
    for (int cb = 0; cb < 4; ++cb) {
      const int krow = cb * 16 + fr;
      shortx8 k0 = *reinterpret_cast<const shortx8*>(
          &Ks[cur][krow * 64 + ((fc ^ (fr & 7)) * 8)]);
      shortx8 k1 = *reinterpret_cast<const shortx8*>(
          &Ks[cur][krow * 64 + (((4 + fc) ^ (fr & 7)) * 8)]);
      #pragma unroll
      for (int rf = 0; rf < 2; ++rf) {
        floatx4 z = {};
        z = __builtin_amdgcn_mfma_f32_16x16x32_bf16(qf[rf][0], k0, z, 0, 0, 0);
        s[rf][cb] = __builtin_amdgcn_mfma_f32_16x16x32_bf16(
            qf[rf][1], k1, z, 0, 0, 0);
      }
    }
    __builtin_amdgcn_s_setprio(0);

    #pragma unroll
    for (int rf = 0; rf < 2; ++rf) {
      #pragma unroll
      for (int cb = 0; cb < 4; ++cb) {
        #pragma unroll
        for (int r = 0; r < 4; ++r) {
          float pv = exp2f(s[rf][cb][r]);
          l_part[rf][r] += pv;
          QPs[(w * 32 + rf * 16 + fc * 4 + r) * 72 + cb * 16 + fr] = f2bf(pv);
        }
      }
    }

    __builtin_amdgcn_s_setprio(1);
    #pragma unroll
    for (int kk = 0; kk < 2; ++kk) {
      shortx8 pf[2];
      #pragma unroll
      for (int rf = 0; rf < 2; ++rf)
        pf[rf] = *reinterpret_cast<const shortx8*>(
            &QPs[(w * 32 + rf * 16 + fr) * 72 + kk * 32 + fc * 8]);
      #pragma unroll
      for (int db = 0; db < 4; ++db) {
        const int vrow = db * 16 + fr;
        shortx8 vf = *reinterpret_cast<const shortx8*>(
            &Vs[cur][vrow * 64 + (((kk * 4 + fc) ^ (fr & 7)) * 8)]);
        #pragma unroll
        for (int rf = 0; rf < 2; ++rf)
          o_acc[rf][db] = __builtin_amdgcn_mfma_f32_16x16x32_bf16(
              pf[rf], vf, o_acc[rf][db], 0, 0, 0);
      }
    }
    __builtin_amdgcn_s_setprio(0);
    __syncthreads();
  }
  #undef STAGE_KV

  float* Ob = Opart + (long)wg * 8192;
  #pragma unroll
  for (int rf = 0; rf < 2; ++rf) {
    #pragma unroll
    for (int r = 0; r < 4; ++r) {
      float l = l_part[rf][r];
      l += __shfl_xor(l, 1);
      l += __shfl_xor(l, 2);
      l += __shfl_xor(l, 4);
      l += __shfl_xor(l, 8);
      const int prow = w * 32 + rf * 16 + fc * 4 + r;
      if (fr == 0) Lpart[(long)wg * 128 + prow] = l;
      #pragma unroll
      for (int db = 0; db < 4; ++db)
        Ob[prow * 64 + db * 16 + fr] = o_acc[rf][db][r];
    }
  }
}

// Combine 4 KV-splits: Aat[b][n][h*64+d] = sum(O_p)/sum(l_p), bf16.
__global__ void k_attn_reduce(const float* __restrict__ Opart,
                              const float* __restrict__ Lpart,
                              unsigned short* __restrict__ Aat) {
  const int tid = threadIdx.x;
  const int g = blockIdx.x * 4 + (tid >> 6);  // row, 0..32767
  const int d = tid & 63;
  const int bh = g >> 9, n = g & 511;
  const int b = bh >> 3, h = bh & 7;
  const int qt = n >> 7, rr = n & 127;
  float o = 0.f, l = 0.f;
  #pragma unroll
  for (int p = 0; p < 4; ++p) {
    const long wgp = ((p * 4 + qt) << 6) + bh;
    o += Opart[wgp * 8192 + rr * 64 + d];
    l += Lpart[wgp * 128 + rr];
  }
  Aat[((long)(b * 512 + n)) * 512 + h * 64 + d] = f2bf(o / l);
}

extern "C" void kernel_launch(void* const* d_in, const int* in_sizes, int n_in,
                              void* d_out, int out_size, void* d_ws, size_t ws_size,
                              hipStream_t stream) {
  const float* x   = (const float*)d_in[0];
  const float* ctx = (const float*)d_in[1];
  const float* Wq  = (const float*)d_in[2];
  const float* Wk  = (const float*)d_in[3];
  const float* Wv  = (const float*)d_in[4];
  const float* Wo  = (const float*)d_in[5];
  const float* bo  = (const float*)d_in[6];
  float* out = (float*)d_out;

  char* ws = (char*)d_ws;
  unsigned short* Qh   = (unsigned short*)(ws);                    // 4MB
  unsigned short* Kh   = (unsigned short*)(ws + (4ull  << 20));    // 32MB
  unsigned short* Vt   = (unsigned short*)(ws + (36ull << 20));    // 32MB
  unsigned short* ctxh = (unsigned short*)(ws + (68ull << 20));    // 64MB
  unsigned short* Aat  = (unsigned short*)(ws + (68ull << 20));    // 4MB, aliases ctxh (dead after proj)
  float*          Opart= (float*)         (ws + (76ull << 20));    // 32MB, inside dead ctxh
  float*          Lpart= (float*)         (ws + (110ull << 20));   // 512KB
  unsigned short* Wqt  = (unsigned short*)(ws + (132ull << 20));   // 1MB
  unsigned short* Wkvt = (unsigned short*)(ws + (133ull << 20));   // 2MB
  unsigned short* Wot  = (unsigned short*)(ws + (135ull << 20));   // 1MB

  k_cvt_bf16<<<dim3(2048), dim3(256), 0, stream>>>(
      ctx, ctxh, (long)B_SZ * M_KV * DIM);

  k_transpose_all<<<dim3(32, 32, 4), dim3(256), 0, stream>>>(
      Wq, Wk, Wv, Wo, Wqt, Wkvt, Wot);

  // combined KV + Q projection (2048 KV tiles + 128 Q tiles)
  k_proj<<<dim3(2176), dim3(256), 0, stream>>>(
      ctxh, x, Wkvt, Wqt, Kh, Vt, Qh);

  // attention: 1024 blocks (4 KV-splits x 4 q-tiles x 64 bh), then combine
  k_attn<<<dim3(1024), dim3(256), 0, stream>>>(Qh, Kh, Vt, Opart, Lpart);
  k_attn_reduce<<<dim3(8192), dim3(256), 0, stream>>>(Opart, Lpart, Aat);

  // output projection + bias, fp32 out
  k_out<<<dim3(256), dim3(256), 0, stream>>>(Aat, Wot, out, bo);
}